// Round 1
// baseline (308.509 us; speedup 1.0000x reference)
//
#include <hip/hip_runtime.h>
#include <stdint.h>

// Problem constants (B, L, D, H) = (8, 256, 512, 512)
#define Bb 8
#define Ll 256
#define Dd 512
#define Hh 512
#define Nout (Ll * Bb * Ll)  // 524288 elements per output tensor

// JAX threefry mode: 1 = partitionable (default since jax 0.4.30), 0 = original
#define RNG_PARTITIONABLE 1

// ---------------------------------------------------------------------------
// Threefry2x32 with key = (0, 42)  (jax.random.key(42))
// ---------------------------------------------------------------------------
__device__ __forceinline__ uint32_t rotl32(uint32_t v, int s) {
  return (v << s) | (v >> (32 - s));
}
__device__ __forceinline__ void tf_round(uint32_t& x0, uint32_t& x1, int r) {
  x0 += x1;
  x1 = rotl32(x1, r);
  x1 ^= x0;
}
__device__ __forceinline__ uint2 threefry2x32_k042(uint32_t x0, uint32_t x1) {
  const uint32_t k0 = 0u;
  const uint32_t k1 = 42u;
  const uint32_t k2 = 0x1BD11BDAu ^ k0 ^ k1;
  x0 += k0; x1 += k1;
  tf_round(x0, x1, 13); tf_round(x0, x1, 15); tf_round(x0, x1, 26); tf_round(x0, x1, 6);
  x0 += k1; x1 += k2 + 1u;
  tf_round(x0, x1, 17); tf_round(x0, x1, 29); tf_round(x0, x1, 16); tf_round(x0, x1, 24);
  x0 += k2; x1 += k0 + 2u;
  tf_round(x0, x1, 13); tf_round(x0, x1, 15); tf_round(x0, x1, 26); tf_round(x0, x1, 6);
  x0 += k0; x1 += k1 + 3u;
  tf_round(x0, x1, 17); tf_round(x0, x1, 29); tf_round(x0, x1, 16); tf_round(x0, x1, 24);
  x0 += k1; x1 += k2 + 4u;
  tf_round(x0, x1, 13); tf_round(x0, x1, 15); tf_round(x0, x1, 26); tf_round(x0, x1, 6);
  x0 += k2; x1 += k0 + 5u;
  return make_uint2(x0, x1);
}

__device__ __forceinline__ uint32_t rng_bits(uint32_t n) {
#if RNG_PARTITIONABLE
  // partitionable: 64-bit counter = n (hi=0, lo=n); 32-bit output = o0 ^ o1
  uint2 o = threefry2x32_k042(0u, n);
  return o.x ^ o.y;
#else
  // original: counts = iota(N), split in half: (x0, x1) = (counts[:N/2], counts[N/2:])
  const uint32_t half = (uint32_t)(Nout / 2);
  if (n < half) {
    uint2 o = threefry2x32_k042(n, n + half);
    return o.x;
  } else {
    uint2 o = threefry2x32_k042(n - half, n);
    return o.y;
  }
#endif
}

// ---------------------------------------------------------------------------
// Kernel 1: dot_l = enc @ W_l, dot_r = enc @ W_r   (fp32 in, fp64 accumulate)
// C[m,h] = sum_k enc[m,k] * W[k,h];  M = B*L = 2048, K = D = 512, N = H = 512
// Tile: 64x64 per block (256 threads), 4x4 micro-tile per thread, BK = 16.
// ---------------------------------------------------------------------------
__global__ __launch_bounds__(256) void gemm_proj(
    const float* __restrict__ enc, const float* __restrict__ Wl,
    const float* __restrict__ Wr, float* __restrict__ dl,
    float* __restrict__ dr) {
  const float* W = (blockIdx.z == 0) ? Wl : Wr;
  float* C = (blockIdx.z == 0) ? dl : dr;
  const int m0 = blockIdx.x * 64;
  const int n0 = blockIdx.y * 64;

  __shared__ float As[64][17];  // +1 pad: breaks 4-way bank alias on broadcast reads
  __shared__ float Ws[16][64];

  const int t = threadIdx.x;
  const int tx = t & 15;  // n direction
  const int ty = t >> 4;  // m direction

  double acc[4][4];
#pragma unroll
  for (int r = 0; r < 4; ++r)
#pragma unroll
    for (int c = 0; c < 4; ++c) acc[r][c] = 0.0;

  for (int k0 = 0; k0 < Dd; k0 += 16) {
    {
      // A tile: 64 rows x 16 cols = 256 float4 loads (one per thread)
      const int r = t >> 2;
      const int c4 = (t & 3) * 4;
      const float4 a = *(const float4*)(enc + (size_t)(m0 + r) * Dd + k0 + c4);
      As[r][c4 + 0] = a.x; As[r][c4 + 1] = a.y;
      As[r][c4 + 2] = a.z; As[r][c4 + 3] = a.w;
      // W tile: 16 rows x 64 cols = 256 float4 loads (one per thread)
      const int kk = t >> 4;
      const int cc = (t & 15) * 4;
      *(float4*)&Ws[kk][cc] = *(const float4*)(W + (size_t)(k0 + kk) * Hh + n0 + cc);
    }
    __syncthreads();
#pragma unroll
    for (int k = 0; k < 16; ++k) {
      const double a0 = (double)As[ty * 4 + 0][k];
      const double a1 = (double)As[ty * 4 + 1][k];
      const double a2 = (double)As[ty * 4 + 2][k];
      const double a3 = (double)As[ty * 4 + 3][k];
      const float4 bf = *(const float4*)&Ws[k][tx * 4];
      const double b0 = bf.x, b1 = bf.y, b2 = bf.z, b3 = bf.w;
      acc[0][0] += a0 * b0; acc[0][1] += a0 * b1; acc[0][2] += a0 * b2; acc[0][3] += a0 * b3;
      acc[1][0] += a1 * b0; acc[1][1] += a1 * b1; acc[1][2] += a1 * b2; acc[1][3] += a1 * b3;
      acc[2][0] += a2 * b0; acc[2][1] += a2 * b1; acc[2][2] += a2 * b2; acc[2][3] += a2 * b3;
      acc[3][0] += a3 * b0; acc[3][1] += a3 * b1; acc[3][2] += a3 * b2; acc[3][3] += a3 * b3;
    }
    __syncthreads();
  }
#pragma unroll
  for (int r = 0; r < 4; ++r) {
    float4 v = make_float4((float)acc[r][0], (float)acc[r][1],
                           (float)acc[r][2], (float)acc[r][3]);
    *(float4*)(C + (size_t)(m0 + ty * 4 + r) * Hh + n0 + tx * 4) = v;
  }
}

// ---------------------------------------------------------------------------
// Kernel 2: for tile (b, i0..i0+15, j0..j0+15):
//   x = sum_h tanh(dl[b,i,h] + dr[b,j,h]) * U[h] + bias;  diag mask -1e8
//   p = sigmoid(x) (fp64 for sample fidelity); sample = threefry-uniform < p
//   entropy = p*softplus(-x) + (1-p)*softplus(x)  (stable form)
// Outputs (all fp32, [L,B,L] row-major): [samples | mask_scores | entropy]
// ---------------------------------------------------------------------------
__global__ __launch_bounds__(256) void biaffine_main(
    const float* __restrict__ dl, const float* __restrict__ dr,
    const float* __restrict__ U, const float* __restrict__ biasp,
    float* __restrict__ out) {
  const int b = blockIdx.z;
  const int i0 = blockIdx.y * 16;
  const int j0 = blockIdx.x * 16;

  // stride 260 floats: 1040 B (16B-aligned for float4); 260 % 32 = 4 so
  // per-row bank base = 4*row -> only 2-way aliasing across 16 rows (free)
  __shared__ float dls[16][260];
  __shared__ float drs[16][260];
  __shared__ float Us[Hh];

  const int t = threadIdx.x;
  if (t < 128) *(float4*)&Us[t * 4] = ((const float4*)U)[t];

  const int ti = t >> 4;
  const int tj = t & 15;

  const float* dlg = dl + (size_t)(b * Ll + i0) * Hh;
  const float* drg = dr + (size_t)(b * Ll + j0) * Hh;

  double acc0 = 0.0, acc1 = 0.0, acc2 = 0.0, acc3 = 0.0;

  for (int ph = 0; ph < 2; ++ph) {
    __syncthreads();
    // stage 16 rows x 256 cols of dl and dr: 1024 float4 each / 256 threads
#pragma unroll
    for (int rep = 0; rep < 4; ++rep) {
      const int idx = t + rep * 256;   // 0..1023
      const int r = idx >> 6;          // 0..15
      const int c = (idx & 63) * 4;    // 0..252
      *(float4*)&dls[r][c] = *(const float4*)(dlg + (size_t)r * Hh + ph * 256 + c);
      *(float4*)&drs[r][c] = *(const float4*)(drg + (size_t)r * Hh + ph * 256 + c);
    }
    __syncthreads();
    const float* arow = &dls[ti][0];
    const float* brow = &drs[tj][0];
    const float* urow = &Us[ph * 256];
#pragma unroll 2
    for (int h = 0; h < 256; h += 4) {
      const float4 a = *(const float4*)&arow[h];
      const float4 bv = *(const float4*)&brow[h];
      const float4 u = *(const float4*)&urow[h];
      acc0 += (double)tanhf(a.x + bv.x) * (double)u.x;
      acc1 += (double)tanhf(a.y + bv.y) * (double)u.y;
      acc2 += (double)tanhf(a.z + bv.z) * (double)u.z;
      acc3 += (double)tanhf(a.w + bv.w) * (double)u.w;
    }
  }

  const int i = i0 + ti;
  const int j = j0 + tj;

  float x = (float)(acc0 + acc1 + acc2 + acc3);
  x += biasp[0];
  if (i == j) x -= 1e8f;  // self-mask, fp32 like the reference

  // sample probability in fp64 (closest to true sigmoid(x_f32))
  const double pd = 1.0 / (1.0 + exp(-(double)x));
  const float pf = (float)pd;

  const uint32_t n = ((uint32_t)i * Bb + (uint32_t)b) * Ll + (uint32_t)j;
  const uint32_t bits = rng_bits(n);
  const float uu = __uint_as_float((bits >> 9) | 0x3f800000u) - 1.0f;
  const float samp = (uu < pf) ? 1.0f : 0.0f;

  // stable softplus pair: softplus(+-x) = max(+-x,0) + log1p(exp(-|x|))
  const float ax = fabsf(x);
  const float l1p = log1pf(expf(-ax));
  const float sp_pos = fmaxf(x, 0.0f) + l1p;
  const float sp_neg = fmaxf(-x, 0.0f) + l1p;
  const float ent = pf * sp_neg + (1.0f - pf) * sp_pos;

  out[n] = samp;
  out[Nout + n] = x;
  out[2 * Nout + n] = ent;
}

// ---------------------------------------------------------------------------
extern "C" void kernel_launch(void* const* d_in, const int* in_sizes, int n_in,
                              void* d_out, int out_size, void* d_ws,
                              size_t ws_size, hipStream_t stream) {
  const float* enc = (const float*)d_in[0];  // [B,L,D]
  const float* Wl = (const float*)d_in[1];   // [D,H]
  const float* Wr = (const float*)d_in[2];   // [D,H]
  const float* U = (const float*)d_in[3];    // [H]
  const float* lb = (const float*)d_in[4];   // [1]
  float* out = (float*)d_out;

  float* dl = (float*)d_ws;                  // [B*L, H] fp32 = 4 MB
  float* dr = dl + (size_t)Bb * Ll * Hh;     // [B*L, H] fp32 = 4 MB

  gemm_proj<<<dim3(2048 / 64, Hh / 64, 2), 256, 0, stream>>>(enc, Wl, Wr, dl, dr);
  biaffine_main<<<dim3(Ll / 16, Ll / 16, Bb), 256, 0, stream>>>(dl, dr, U, lb, out);
}

// Round 2
// 189.415 us; speedup vs baseline: 1.6287x; 1.6287x over previous
//
#include <hip/hip_runtime.h>
#include <stdint.h>

// Problem constants (B, L, D, H) = (8, 256, 512, 512)
#define Bb 8
#define Ll 256
#define Dd 512
#define Hh 512
#define Nout (Ll * Bb * Ll)  // 524288 elements per output tensor

// JAX threefry mode: 1 = partitionable (default since jax 0.4.30), 0 = original
#define RNG_PARTITIONABLE 1

// ---------------------------------------------------------------------------
// Threefry2x32 with key = (0, 42)  (jax.random.key(42))
// ---------------------------------------------------------------------------
__device__ __forceinline__ uint32_t rotl32(uint32_t v, int s) {
  return (v << s) | (v >> (32 - s));
}
__device__ __forceinline__ void tf_round(uint32_t& x0, uint32_t& x1, int r) {
  x0 += x1;
  x1 = rotl32(x1, r);
  x1 ^= x0;
}
__device__ __forceinline__ uint2 threefry2x32_k042(uint32_t x0, uint32_t x1) {
  const uint32_t k0 = 0u;
  const uint32_t k1 = 42u;
  const uint32_t k2 = 0x1BD11BDAu ^ k0 ^ k1;
  x0 += k0; x1 += k1;
  tf_round(x0, x1, 13); tf_round(x0, x1, 15); tf_round(x0, x1, 26); tf_round(x0, x1, 6);
  x0 += k1; x1 += k2 + 1u;
  tf_round(x0, x1, 17); tf_round(x0, x1, 29); tf_round(x0, x1, 16); tf_round(x0, x1, 24);
  x0 += k2; x1 += k0 + 2u;
  tf_round(x0, x1, 13); tf_round(x0, x1, 15); tf_round(x0, x1, 26); tf_round(x0, x1, 6);
  x0 += k0; x1 += k1 + 3u;
  tf_round(x0, x1, 17); tf_round(x0, x1, 29); tf_round(x0, x1, 16); tf_round(x0, x1, 24);
  x0 += k1; x1 += k2 + 4u;
  tf_round(x0, x1, 13); tf_round(x0, x1, 15); tf_round(x0, x1, 26); tf_round(x0, x1, 6);
  x0 += k2; x1 += k0 + 5u;
  return make_uint2(x0, x1);
}

__device__ __forceinline__ uint32_t rng_bits(uint32_t n) {
#if RNG_PARTITIONABLE
  uint2 o = threefry2x32_k042(0u, n);
  return o.x ^ o.y;
#else
  const uint32_t half = (uint32_t)(Nout / 2);
  if (n < half) {
    uint2 o = threefry2x32_k042(n, n + half);
    return o.x;
  } else {
    uint2 o = threefry2x32_k042(n - half, n);
    return o.y;
  }
#endif
}

// ---------------------------------------------------------------------------
// fast_tanh: tanh(s) = 1 - 2/(exp2(s*2*log2e) + 1)   (exact identity)
// 5 VALU instrs: mul, v_exp_f32, add, v_rcp_f32, fma. Abs error ~1e-7.
// Saturates correctly: s>>0 -> exp2=inf -> rcp=0 -> 1;  s<<0 -> exp2=0 -> -1.
// ---------------------------------------------------------------------------
__device__ __forceinline__ float fast_tanh(float s) {
  const float K = 2.8853900817779268f;  // 2/ln(2)
  float t = __builtin_amdgcn_exp2f(s * K);
  float r = __builtin_amdgcn_rcpf(t + 1.0f);
  return __builtin_fmaf(-2.0f, r, 1.0f);
}

// ---------------------------------------------------------------------------
// Kernel 1: dot_l = enc @ W_l, dot_r = enc @ W_r
// fp32 FMA inner loop (b128 LDS reads), promoted to fp64 once per 16-k block.
// Tile: 64x64 per block (256 threads), 4x4 micro-tile per thread, BK = 16.
// A-tile stored TRANSPOSED in LDS (As[k][m]) so fragment reads are float4.
// ---------------------------------------------------------------------------
__global__ __launch_bounds__(256) void gemm_proj(
    const float* __restrict__ enc, const float* __restrict__ Wl,
    const float* __restrict__ Wr, float* __restrict__ dl,
    float* __restrict__ dr) {
  const float* W = (blockIdx.z == 0) ? Wl : Wr;
  float* C = (blockIdx.z == 0) ? dl : dr;
  const int m0 = blockIdx.x * 64;
  const int n0 = blockIdx.y * 64;

  __shared__ float As[16][68];  // As[k][m], stride 68 (272 B, 16B-aligned)
  __shared__ float Ws[16][68];  // Ws[k][n]

  const int t = threadIdx.x;
  const int tx = t & 15;  // n direction
  const int ty = t >> 4;  // m direction

  double accd[4][4];
#pragma unroll
  for (int r = 0; r < 4; ++r)
#pragma unroll
    for (int c = 0; c < 4; ++c) accd[r][c] = 0.0;

  for (int k0 = 0; k0 < Dd; k0 += 16) {
    {
      // A tile: 64 rows x 16 k — one float4 per thread, stored transposed
      const int r = t >> 2;
      const int c4 = (t & 3) * 4;
      const float4 a = *(const float4*)(enc + (size_t)(m0 + r) * Dd + k0 + c4);
      As[c4 + 0][r] = a.x; As[c4 + 1][r] = a.y;
      As[c4 + 2][r] = a.z; As[c4 + 3][r] = a.w;
      // W tile: 16 k x 64 n — one float4 per thread
      const int kk = t >> 4;
      const int cc = (t & 15) * 4;
      *(float4*)&Ws[kk][cc] = *(const float4*)(W + (size_t)(k0 + kk) * Hh + n0 + cc);
    }
    __syncthreads();

    float accf[4][4];
#pragma unroll
    for (int r = 0; r < 4; ++r)
#pragma unroll
      for (int c = 0; c < 4; ++c) accf[r][c] = 0.0f;

#pragma unroll
    for (int k = 0; k < 16; ++k) {
      const float4 av = *(const float4*)&As[k][ty * 4];
      const float4 bv = *(const float4*)&Ws[k][tx * 4];
      accf[0][0] = __builtin_fmaf(av.x, bv.x, accf[0][0]);
      accf[0][1] = __builtin_fmaf(av.x, bv.y, accf[0][1]);
      accf[0][2] = __builtin_fmaf(av.x, bv.z, accf[0][2]);
      accf[0][3] = __builtin_fmaf(av.x, bv.w, accf[0][3]);
      accf[1][0] = __builtin_fmaf(av.y, bv.x, accf[1][0]);
      accf[1][1] = __builtin_fmaf(av.y, bv.y, accf[1][1]);
      accf[1][2] = __builtin_fmaf(av.y, bv.z, accf[1][2]);
      accf[1][3] = __builtin_fmaf(av.y, bv.w, accf[1][3]);
      accf[2][0] = __builtin_fmaf(av.z, bv.x, accf[2][0]);
      accf[2][1] = __builtin_fmaf(av.z, bv.y, accf[2][1]);
      accf[2][2] = __builtin_fmaf(av.z, bv.z, accf[2][2]);
      accf[2][3] = __builtin_fmaf(av.z, bv.w, accf[2][3]);
      accf[3][0] = __builtin_fmaf(av.w, bv.x, accf[3][0]);
      accf[3][1] = __builtin_fmaf(av.w, bv.y, accf[3][1]);
      accf[3][2] = __builtin_fmaf(av.w, bv.z, accf[3][2]);
      accf[3][3] = __builtin_fmaf(av.w, bv.w, accf[3][3]);
    }
#pragma unroll
    for (int r = 0; r < 4; ++r)
#pragma unroll
      for (int c = 0; c < 4; ++c) accd[r][c] += (double)accf[r][c];
    __syncthreads();
  }
#pragma unroll
  for (int r = 0; r < 4; ++r) {
    float4 v = make_float4((float)accd[r][0], (float)accd[r][1],
                           (float)accd[r][2], (float)accd[r][3]);
    *(float4*)(C + (size_t)(m0 + ty * 4 + r) * Hh + n0 + tx * 4) = v;
  }
}

// ---------------------------------------------------------------------------
// Kernel 2: x[b,i,j] = sum_h tanh(dl[b,i,h]+dr[b,j,h])*U[h] + bias; diag -1e8
// p = sigmoid(x) in fp64; sample = threefry-uniform < p; stable entropy.
// Per-term fp64 accumulation (product in fp32: err ~1.5e-9/term, negligible).
// ---------------------------------------------------------------------------
__global__ __launch_bounds__(256) void biaffine_main(
    const float* __restrict__ dl, const float* __restrict__ dr,
    const float* __restrict__ U, const float* __restrict__ biasp,
    float* __restrict__ out) {
  const int b = blockIdx.z;
  const int i0 = blockIdx.y * 16;
  const int j0 = blockIdx.x * 16;

  // stride 260 floats (1040 B, 16B-aligned); 260 % 32 = 4 -> 2-way alias (free)
  __shared__ float dls[16][260];
  __shared__ float drs[16][260];
  __shared__ float Us[Hh];

  const int t = threadIdx.x;
  if (t < 128) *(float4*)&Us[t * 4] = ((const float4*)U)[t];

  const int ti = t >> 4;
  const int tj = t & 15;

  const float* dlg = dl + (size_t)(b * Ll + i0) * Hh;
  const float* drg = dr + (size_t)(b * Ll + j0) * Hh;

  double acc0 = 0.0, acc1 = 0.0, acc2 = 0.0, acc3 = 0.0;

  for (int ph = 0; ph < 2; ++ph) {
    __syncthreads();
#pragma unroll
    for (int rep = 0; rep < 4; ++rep) {
      const int idx = t + rep * 256;   // 0..1023
      const int r = idx >> 6;          // 0..15
      const int c = (idx & 63) * 4;    // 0..252
      *(float4*)&dls[r][c] = *(const float4*)(dlg + (size_t)r * Hh + ph * 256 + c);
      *(float4*)&drs[r][c] = *(const float4*)(drg + (size_t)r * Hh + ph * 256 + c);
    }
    __syncthreads();
    const float* arow = &dls[ti][0];
    const float* brow = &drs[tj][0];
    const float* urow = &Us[ph * 256];
#pragma unroll 2
    for (int h = 0; h < 256; h += 4) {
      const float4 a = *(const float4*)&arow[h];
      const float4 bv = *(const float4*)&brow[h];
      const float4 u = *(const float4*)&urow[h];
      acc0 += (double)(fast_tanh(a.x + bv.x) * u.x);
      acc1 += (double)(fast_tanh(a.y + bv.y) * u.y);
      acc2 += (double)(fast_tanh(a.z + bv.z) * u.z);
      acc3 += (double)(fast_tanh(a.w + bv.w) * u.w);
    }
  }

  const int i = i0 + ti;
  const int j = j0 + tj;

  float x = (float)(acc0 + acc1 + acc2 + acc3);
  x += biasp[0];
  if (i == j) x -= 1e8f;  // self-mask, fp32 like the reference

  const double pd = 1.0 / (1.0 + exp(-(double)x));
  const float pf = (float)pd;

  const uint32_t n = ((uint32_t)i * Bb + (uint32_t)b) * Ll + (uint32_t)j;
  const uint32_t bits = rng_bits(n);
  const float uu = __uint_as_float((bits >> 9) | 0x3f800000u) - 1.0f;
  const float samp = (uu < pf) ? 1.0f : 0.0f;

  // stable softplus pair: softplus(+-x) = max(+-x,0) + log1p(exp(-|x|))
  const float ax = fabsf(x);
  const float l1p = log1pf(expf(-ax));
  const float sp_pos = fmaxf(x, 0.0f) + l1p;
  const float sp_neg = fmaxf(-x, 0.0f) + l1p;
  const float ent = pf * sp_neg + (1.0f - pf) * sp_pos;

  out[n] = samp;
  out[Nout + n] = x;
  out[2 * Nout + n] = ent;
}

// ---------------------------------------------------------------------------
extern "C" void kernel_launch(void* const* d_in, const int* in_sizes, int n_in,
                              void* d_out, int out_size, void* d_ws,
                              size_t ws_size, hipStream_t stream) {
  const float* enc = (const float*)d_in[0];  // [B,L,D]
  const float* Wl = (const float*)d_in[1];   // [D,H]
  const float* Wr = (const float*)d_in[2];   // [D,H]
  const float* U = (const float*)d_in[3];    // [H]
  const float* lb = (const float*)d_in[4];   // [1]
  float* out = (float*)d_out;

  float* dl = (float*)d_ws;                  // [B*L, H] fp32 = 4 MB
  float* dr = dl + (size_t)Bb * Ll * Hh;     // [B*L, H] fp32 = 4 MB

  gemm_proj<<<dim3(2048 / 64, Hh / 64, 2), 256, 0, stream>>>(enc, Wl, Wr, dl, dr);
  biaffine_main<<<dim3(Ll / 16, Ll / 16, Bb), 256, 0, stream>>>(dl, dr, U, lb, out);
}

// Round 3
// 149.342 us; speedup vs baseline: 2.0658x; 1.2683x over previous
//
#include <hip/hip_runtime.h>
#include <stdint.h>

// Problem constants (B, L, D, H) = (8, 256, 512, 512)
#define Bb 8
#define Ll 256
#define Dd 512
#define Hh 512
#define Nout (Ll * Bb * Ll)  // 524288 elements per output tensor

#define Kc 2.8853900817779268  // 2/ln(2):  exp2(Kc*s) = e^(2s)

// JAX threefry mode: 1 = partitionable (default since jax 0.4.30)
#define RNG_PARTITIONABLE 1

// ---------------------------------------------------------------------------
// Threefry2x32 with key = (0, 42)  (jax.random.key(42))
// ---------------------------------------------------------------------------
__device__ __forceinline__ uint32_t rotl32(uint32_t v, int s) {
  return (v << s) | (v >> (32 - s));
}
__device__ __forceinline__ void tf_round(uint32_t& x0, uint32_t& x1, int r) {
  x0 += x1;
  x1 = rotl32(x1, r);
  x1 ^= x0;
}
__device__ __forceinline__ uint2 threefry2x32_k042(uint32_t x0, uint32_t x1) {
  const uint32_t k0 = 0u;
  const uint32_t k1 = 42u;
  const uint32_t k2 = 0x1BD11BDAu ^ k0 ^ k1;
  x0 += k0; x1 += k1;
  tf_round(x0, x1, 13); tf_round(x0, x1, 15); tf_round(x0, x1, 26); tf_round(x0, x1, 6);
  x0 += k1; x1 += k2 + 1u;
  tf_round(x0, x1, 17); tf_round(x0, x1, 29); tf_round(x0, x1, 16); tf_round(x0, x1, 24);
  x0 += k2; x1 += k0 + 2u;
  tf_round(x0, x1, 13); tf_round(x0, x1, 15); tf_round(x0, x1, 26); tf_round(x0, x1, 6);
  x0 += k0; x1 += k1 + 3u;
  tf_round(x0, x1, 17); tf_round(x0, x1, 29); tf_round(x0, x1, 16); tf_round(x0, x1, 24);
  x0 += k1; x1 += k2 + 4u;
  tf_round(x0, x1, 13); tf_round(x0, x1, 15); tf_round(x0, x1, 26); tf_round(x0, x1, 6);
  x0 += k2; x1 += k0 + 5u;
  return make_uint2(x0, x1);
}

__device__ __forceinline__ uint32_t rng_bits(uint32_t n) {
#if RNG_PARTITIONABLE
  uint2 o = threefry2x32_k042(0u, n);
  return o.x ^ o.y;
#else
  const uint32_t half = (uint32_t)(Nout / 2);
  if (n < half) {
    uint2 o = threefry2x32_k042(n, n + half);
    return o.x;
  } else {
    uint2 o = threefry2x32_k042(n - half, n);
    return o.y;
  }
#endif
}

// ---------------------------------------------------------------------------
// Kernel 1: el = exp2(Kc * (enc @ W_l)),  er = exp2(Kc * (enc @ W_r))
// fp32 FMA inner (b128 LDS reads), fp64 promotion once per 32-k block.
// 64x64 tile / 256 threads / 4x4 micro-tile. BK=32, double-buffered LDS with
// register prefetch: one barrier per k-step, load latency hidden by compute.
// ---------------------------------------------------------------------------
__global__ __launch_bounds__(256) void gemm_proj(
    const float* __restrict__ enc, const float* __restrict__ Wl,
    const float* __restrict__ Wr, float* __restrict__ el,
    float* __restrict__ er) {
  const float* W = (blockIdx.z == 0) ? Wl : Wr;
  float* C = (blockIdx.z == 0) ? el : er;
  const int m0 = blockIdx.x * 64;
  const int n0 = blockIdx.y * 64;

  // As[buf][k][m] (transposed), Ws[buf][k][n]; stride 68 keeps b128 16B-aligned
  __shared__ float As[2][32][68];
  __shared__ float Ws[2][32][68];

  const int t = threadIdx.x;
  const int tx = t & 15;  // n direction
  const int ty = t >> 4;  // m direction

  double accd[4][4];
#pragma unroll
  for (int r = 0; r < 4; ++r)
#pragma unroll
    for (int c = 0; c < 4; ++c) accd[r][c] = 0.0;

  float4 pa[2], pw[2];
  // prologue: load k-step 0
#pragma unroll
  for (int r = 0; r < 2; ++r) {
    const int idx = t + r * 256;
    const int am = idx >> 3, akq = idx & 7;       // A: 64 m x 8 float4-k
    pa[r] = *(const float4*)(enc + (size_t)(m0 + am) * Dd + akq * 4);
    const int wk = idx >> 4, wnq = idx & 15;      // W: 32 k x 16 float4-n
    pw[r] = *(const float4*)(W + (size_t)wk * Hh + n0 + wnq * 4);
  }
#pragma unroll
  for (int r = 0; r < 2; ++r) {
    const int idx = t + r * 256;
    const int am = idx >> 3, akq = idx & 7;
    As[0][akq * 4 + 0][am] = pa[r].x;
    As[0][akq * 4 + 1][am] = pa[r].y;
    As[0][akq * 4 + 2][am] = pa[r].z;
    As[0][akq * 4 + 3][am] = pa[r].w;
    const int wk = idx >> 4, wnq = idx & 15;
    *(float4*)&Ws[0][wk][wnq * 4] = pw[r];
  }
  __syncthreads();

  for (int s = 0; s < 16; ++s) {
    const int buf = s & 1;
    if (s < 15) {
      const int k0 = (s + 1) * 32;
#pragma unroll
      for (int r = 0; r < 2; ++r) {
        const int idx = t + r * 256;
        const int am = idx >> 3, akq = idx & 7;
        pa[r] = *(const float4*)(enc + (size_t)(m0 + am) * Dd + k0 + akq * 4);
        const int wk = idx >> 4, wnq = idx & 15;
        pw[r] = *(const float4*)(W + (size_t)(k0 + wk) * Hh + n0 + wnq * 4);
      }
    }

    float accf[4][4];
#pragma unroll
    for (int r = 0; r < 4; ++r)
#pragma unroll
      for (int c = 0; c < 4; ++c) accf[r][c] = 0.0f;

#pragma unroll
    for (int k = 0; k < 32; ++k) {
      const float4 av = *(const float4*)&As[buf][k][ty * 4];
      const float4 bv = *(const float4*)&Ws[buf][k][tx * 4];
      accf[0][0] = __builtin_fmaf(av.x, bv.x, accf[0][0]);
      accf[0][1] = __builtin_fmaf(av.x, bv.y, accf[0][1]);
      accf[0][2] = __builtin_fmaf(av.x, bv.z, accf[0][2]);
      accf[0][3] = __builtin_fmaf(av.x, bv.w, accf[0][3]);
      accf[1][0] = __builtin_fmaf(av.y, bv.x, accf[1][0]);
      accf[1][1] = __builtin_fmaf(av.y, bv.y, accf[1][1]);
      accf[1][2] = __builtin_fmaf(av.y, bv.z, accf[1][2]);
      accf[1][3] = __builtin_fmaf(av.y, bv.w, accf[1][3]);
      accf[2][0] = __builtin_fmaf(av.z, bv.x, accf[2][0]);
      accf[2][1] = __builtin_fmaf(av.z, bv.y, accf[2][1]);
      accf[2][2] = __builtin_fmaf(av.z, bv.z, accf[2][2]);
      accf[2][3] = __builtin_fmaf(av.z, bv.w, accf[2][3]);
      accf[3][0] = __builtin_fmaf(av.w, bv.x, accf[3][0]);
      accf[3][1] = __builtin_fmaf(av.w, bv.y, accf[3][1]);
      accf[3][2] = __builtin_fmaf(av.w, bv.z, accf[3][2]);
      accf[3][3] = __builtin_fmaf(av.w, bv.w, accf[3][3]);
    }
#pragma unroll
    for (int r = 0; r < 4; ++r)
#pragma unroll
      for (int c = 0; c < 4; ++c) accd[r][c] += (double)accf[r][c];

    if (s < 15) {
      const int nb = buf ^ 1;
#pragma unroll
      for (int r = 0; r < 2; ++r) {
        const int idx = t + r * 256;
        const int am = idx >> 3, akq = idx & 7;
        As[nb][akq * 4 + 0][am] = pa[r].x;
        As[nb][akq * 4 + 1][am] = pa[r].y;
        As[nb][akq * 4 + 2][am] = pa[r].z;
        As[nb][akq * 4 + 3][am] = pa[r].w;
        const int wk = idx >> 4, wnq = idx & 15;
        *(float4*)&Ws[nb][wk][wnq * 4] = pw[r];
      }
    }
    __syncthreads();
  }

  // epilogue: store exp2(Kc * dot) so the biaffine inner loop needs no exp
#pragma unroll
  for (int r = 0; r < 4; ++r) {
    float4 v;
    v.x = __builtin_amdgcn_exp2f((float)(Kc * accd[r][0]));
    v.y = __builtin_amdgcn_exp2f((float)(Kc * accd[r][1]));
    v.z = __builtin_amdgcn_exp2f((float)(Kc * accd[r][2]));
    v.w = __builtin_amdgcn_exp2f((float)(Kc * accd[r][3]));
    *(float4*)(C + (size_t)(m0 + ty * 4 + r) * Hh + n0 + tx * 4) = v;
  }
}

// ---------------------------------------------------------------------------
// Kernel 2: x[b,i,j] = sum_h tanh(dl+dr)*u + bias, via e = el*er and
//   tanh = 1 - 2/(1+e). 4-term common-denominator groups -> 1 rcp / 4 terms:
//   group = us4 - 2*(u0*d1*d2*d3 + u1*d0*d2*d3 + ...)/(d0*d1*d2*d3)
// No transcendentals in the h-loop except one v_rcp per 4 terms.
// ---------------------------------------------------------------------------
__global__ __launch_bounds__(256) void biaffine_main(
    const float* __restrict__ el, const float* __restrict__ er,
    const float* __restrict__ U, const float* __restrict__ biasp,
    float* __restrict__ out) {
  const int b = blockIdx.z;
  const int i0 = blockIdx.y * 16;
  const int j0 = blockIdx.x * 16;

  // stride 260 floats (16B-aligned rows); 260 % 32 = 4 -> 2-way alias (free)
  __shared__ float els[16][260];
  __shared__ float ers[16][260];
  __shared__ float us[Hh];
  __shared__ float us4[Hh / 4];

  const int t = threadIdx.x;
  if (t < 128) {
    const float4 u = ((const float4*)U)[t];
    *(float4*)&us[t * 4] = u;
    us4[t] = ((u.x + u.y) + u.z) + u.w;  // group sums for the identity above
  }

  const int ti = t >> 4;
  const int tj = t & 15;

  const float* elg = el + (size_t)(b * Ll + i0) * Hh;
  const float* erg = er + (size_t)(b * Ll + j0) * Hh;

  float acc[4] = {0.0f, 0.0f, 0.0f, 0.0f};

  for (int ph = 0; ph < 2; ++ph) {
    __syncthreads();
#pragma unroll
    for (int rep = 0; rep < 4; ++rep) {
      const int idx = t + rep * 256;   // 0..1023
      const int r = idx >> 6;          // 0..15
      const int c = (idx & 63) * 4;    // 0..252
      *(float4*)&els[r][c] = *(const float4*)(elg + (size_t)r * Hh + ph * 256 + c);
      *(float4*)&ers[r][c] = *(const float4*)(erg + (size_t)r * Hh + ph * 256 + c);
    }
    __syncthreads();
    const float* arow = &els[ti][0];
    const float* brow = &ers[tj][0];
    const float* urow = &us[ph * 256];
    const float* u4row = &us4[ph * 64];
#pragma unroll 2
    for (int g = 0; g < 64; ++g) {
      const int h = g * 4;
      const float4 a = *(const float4*)&arow[h];
      const float4 bv = *(const float4*)&brow[h];
      const float4 u = *(const float4*)&urow[h];
      const float s4 = u4row[g];
      const float d0 = __builtin_fmaf(a.x, bv.x, 1.0f);
      const float d1 = __builtin_fmaf(a.y, bv.y, 1.0f);
      const float d2 = __builtin_fmaf(a.z, bv.z, 1.0f);
      const float d3 = __builtin_fmaf(a.w, bv.w, 1.0f);
      const float p01 = d0 * d1;
      const float p23 = d2 * d3;
      const float D = p01 * p23;
      float n01 = u.x * d1;
      n01 = __builtin_fmaf(u.y, d0, n01);
      float n23 = u.z * d3;
      n23 = __builtin_fmaf(u.w, d2, n23);
      float num = n01 * p23;
      num = __builtin_fmaf(n23, p01, num);
      const float r = __builtin_amdgcn_rcpf(D);
      const float nr = num * r;
      acc[g & 3] += __builtin_fmaf(-2.0f, nr, s4);
    }
  }

  const int i = i0 + ti;
  const int j = j0 + tj;

  float x = (float)((((double)acc[0] + (double)acc[1]) +
                     ((double)acc[2] + (double)acc[3])));
  x += biasp[0];
  if (i == j) x -= 1e8f;  // self-mask, fp32 like the reference

  const double pd = 1.0 / (1.0 + exp(-(double)x));
  const float pf = (float)pd;

  const uint32_t n = ((uint32_t)i * Bb + (uint32_t)b) * Ll + (uint32_t)j;
  const uint32_t bits = rng_bits(n);
  const float uu = __uint_as_float((bits >> 9) | 0x3f800000u) - 1.0f;
  const float samp = (uu < pf) ? 1.0f : 0.0f;

  // stable softplus pair: softplus(+-x) = max(+-x,0) + log1p(exp(-|x|))
  const float ax = fabsf(x);
  const float l1p = log1pf(expf(-ax));
  const float sp_pos = fmaxf(x, 0.0f) + l1p;
  const float sp_neg = fmaxf(-x, 0.0f) + l1p;
  const float ent = pf * sp_neg + (1.0f - pf) * sp_pos;

  out[n] = samp;
  out[Nout + n] = x;
  out[2 * Nout + n] = ent;
}

// ---------------------------------------------------------------------------
extern "C" void kernel_launch(void* const* d_in, const int* in_sizes, int n_in,
                              void* d_out, int out_size, void* d_ws,
                              size_t ws_size, hipStream_t stream) {
  const float* enc = (const float*)d_in[0];  // [B,L,D]
  const float* Wl = (const float*)d_in[1];   // [D,H]
  const float* Wr = (const float*)d_in[2];   // [D,H]
  const float* U = (const float*)d_in[3];    // [H]
  const float* lb = (const float*)d_in[4];   // [1]
  float* out = (float*)d_out;

  float* el = (float*)d_ws;                  // exp2(Kc*dot_l): [B*L, H] = 4 MB
  float* er = el + (size_t)Bb * Ll * Hh;     // exp2(Kc*dot_r): [B*L, H] = 4 MB

  gemm_proj<<<dim3(2048 / 64, Hh / 64, 2), 256, 0, stream>>>(enc, Wl, Wr, el, er);
  biaffine_main<<<dim3(Ll / 16, Ll / 16, Bb), 256, 0, stream>>>(el, er, U, lb, out);
}

// Round 4
// 134.635 us; speedup vs baseline: 2.2915x; 1.1092x over previous
//
#include <hip/hip_runtime.h>
#include <stdint.h>

// Problem constants (B, L, D, H) = (8, 256, 512, 512)
#define Bb 8
#define Ll 256
#define Dd 512
#define Hh 512
#define Nout (Ll * Bb * Ll)  // 524288 elements per output tensor

#define Kc 2.8853900817779268  // 2/ln(2):  exp2(Kc*s) = e^(2s)

// JAX threefry mode: 1 = partitionable (default since jax 0.4.30)
#define RNG_PARTITIONABLE 1

// ---------------------------------------------------------------------------
// Threefry2x32 with key = (0, 42)  (jax.random.key(42))
// ---------------------------------------------------------------------------
__device__ __forceinline__ uint32_t rotl32(uint32_t v, int s) {
  return (v << s) | (v >> (32 - s));
}
__device__ __forceinline__ void tf_round(uint32_t& x0, uint32_t& x1, int r) {
  x0 += x1;
  x1 = rotl32(x1, r);
  x1 ^= x0;
}
__device__ __forceinline__ uint2 threefry2x32_k042(uint32_t x0, uint32_t x1) {
  const uint32_t k0 = 0u;
  const uint32_t k1 = 42u;
  const uint32_t k2 = 0x1BD11BDAu ^ k0 ^ k1;
  x0 += k0; x1 += k1;
  tf_round(x0, x1, 13); tf_round(x0, x1, 15); tf_round(x0, x1, 26); tf_round(x0, x1, 6);
  x0 += k1; x1 += k2 + 1u;
  tf_round(x0, x1, 17); tf_round(x0, x1, 29); tf_round(x0, x1, 16); tf_round(x0, x1, 24);
  x0 += k2; x1 += k0 + 2u;
  tf_round(x0, x1, 13); tf_round(x0, x1, 15); tf_round(x0, x1, 26); tf_round(x0, x1, 6);
  x0 += k0; x1 += k1 + 3u;
  tf_round(x0, x1, 17); tf_round(x0, x1, 29); tf_round(x0, x1, 16); tf_round(x0, x1, 24);
  x0 += k1; x1 += k2 + 4u;
  tf_round(x0, x1, 13); tf_round(x0, x1, 15); tf_round(x0, x1, 26); tf_round(x0, x1, 6);
  x0 += k2; x1 += k0 + 5u;
  return make_uint2(x0, x1);
}

__device__ __forceinline__ uint32_t rng_bits(uint32_t n) {
#if RNG_PARTITIONABLE
  uint2 o = threefry2x32_k042(0u, n);
  return o.x ^ o.y;
#else
  const uint32_t half = (uint32_t)(Nout / 2);
  if (n < half) {
    uint2 o = threefry2x32_k042(n, n + half);
    return o.x;
  } else {
    uint2 o = threefry2x32_k042(n - half, n);
    return o.y;
  }
#endif
}

// ---------------------------------------------------------------------------
// Kernel 1: el = exp2(Kc * (enc @ W_l)),  er = exp2(Kc * (enc @ W_r))
// (unchanged from R3 for attribution)
// ---------------------------------------------------------------------------
__global__ __launch_bounds__(256) void gemm_proj(
    const float* __restrict__ enc, const float* __restrict__ Wl,
    const float* __restrict__ Wr, float* __restrict__ el,
    float* __restrict__ er) {
  const float* W = (blockIdx.z == 0) ? Wl : Wr;
  float* C = (blockIdx.z == 0) ? el : er;
  const int m0 = blockIdx.x * 64;
  const int n0 = blockIdx.y * 64;

  __shared__ float As[2][32][68];
  __shared__ float Ws[2][32][68];

  const int t = threadIdx.x;
  const int tx = t & 15;
  const int ty = t >> 4;

  double accd[4][4];
#pragma unroll
  for (int r = 0; r < 4; ++r)
#pragma unroll
    for (int c = 0; c < 4; ++c) accd[r][c] = 0.0;

  float4 pa[2], pw[2];
#pragma unroll
  for (int r = 0; r < 2; ++r) {
    const int idx = t + r * 256;
    const int am = idx >> 3, akq = idx & 7;
    pa[r] = *(const float4*)(enc + (size_t)(m0 + am) * Dd + akq * 4);
    const int wk = idx >> 4, wnq = idx & 15;
    pw[r] = *(const float4*)(W + (size_t)wk * Hh + n0 + wnq * 4);
  }
#pragma unroll
  for (int r = 0; r < 2; ++r) {
    const int idx = t + r * 256;
    const int am = idx >> 3, akq = idx & 7;
    As[0][akq * 4 + 0][am] = pa[r].x;
    As[0][akq * 4 + 1][am] = pa[r].y;
    As[0][akq * 4 + 2][am] = pa[r].z;
    As[0][akq * 4 + 3][am] = pa[r].w;
    const int wk = idx >> 4, wnq = idx & 15;
    *(float4*)&Ws[0][wk][wnq * 4] = pw[r];
  }
  __syncthreads();

  for (int s = 0; s < 16; ++s) {
    const int buf = s & 1;
    if (s < 15) {
      const int k0 = (s + 1) * 32;
#pragma unroll
      for (int r = 0; r < 2; ++r) {
        const int idx = t + r * 256;
        const int am = idx >> 3, akq = idx & 7;
        pa[r] = *(const float4*)(enc + (size_t)(m0 + am) * Dd + k0 + akq * 4);
        const int wk = idx >> 4, wnq = idx & 15;
        pw[r] = *(const float4*)(W + (size_t)(k0 + wk) * Hh + n0 + wnq * 4);
      }
    }

    float accf[4][4];
#pragma unroll
    for (int r = 0; r < 4; ++r)
#pragma unroll
      for (int c = 0; c < 4; ++c) accf[r][c] = 0.0f;

#pragma unroll
    for (int k = 0; k < 32; ++k) {
      const float4 av = *(const float4*)&As[buf][k][ty * 4];
      const float4 bv = *(const float4*)&Ws[buf][k][tx * 4];
      accf[0][0] = __builtin_fmaf(av.x, bv.x, accf[0][0]);
      accf[0][1] = __builtin_fmaf(av.x, bv.y, accf[0][1]);
      accf[0][2] = __builtin_fmaf(av.x, bv.z, accf[0][2]);
      accf[0][3] = __builtin_fmaf(av.x, bv.w, accf[0][3]);
      accf[1][0] = __builtin_fmaf(av.y, bv.x, accf[1][0]);
      accf[1][1] = __builtin_fmaf(av.y, bv.y, accf[1][1]);
      accf[1][2] = __builtin_fmaf(av.y, bv.z, accf[1][2]);
      accf[1][3] = __builtin_fmaf(av.y, bv.w, accf[1][3]);
      accf[2][0] = __builtin_fmaf(av.z, bv.x, accf[2][0]);
      accf[2][1] = __builtin_fmaf(av.z, bv.y, accf[2][1]);
      accf[2][2] = __builtin_fmaf(av.z, bv.z, accf[2][2]);
      accf[2][3] = __builtin_fmaf(av.z, bv.w, accf[2][3]);
      accf[3][0] = __builtin_fmaf(av.w, bv.x, accf[3][0]);
      accf[3][1] = __builtin_fmaf(av.w, bv.y, accf[3][1]);
      accf[3][2] = __builtin_fmaf(av.w, bv.z, accf[3][2]);
      accf[3][3] = __builtin_fmaf(av.w, bv.w, accf[3][3]);
    }
#pragma unroll
    for (int r = 0; r < 4; ++r)
#pragma unroll
      for (int c = 0; c < 4; ++c) accd[r][c] += (double)accf[r][c];

    if (s < 15) {
      const int nb = buf ^ 1;
#pragma unroll
      for (int r = 0; r < 2; ++r) {
        const int idx = t + r * 256;
        const int am = idx >> 3, akq = idx & 7;
        As[nb][akq * 4 + 0][am] = pa[r].x;
        As[nb][akq * 4 + 1][am] = pa[r].y;
        As[nb][akq * 4 + 2][am] = pa[r].z;
        As[nb][akq * 4 + 3][am] = pa[r].w;
        const int wk = idx >> 4, wnq = idx & 15;
        *(float4*)&Ws[nb][wk][wnq * 4] = pw[r];
      }
    }
    __syncthreads();
  }

#pragma unroll
  for (int r = 0; r < 4; ++r) {
    float4 v;
    v.x = __builtin_amdgcn_exp2f((float)(Kc * accd[r][0]));
    v.y = __builtin_amdgcn_exp2f((float)(Kc * accd[r][1]));
    v.z = __builtin_amdgcn_exp2f((float)(Kc * accd[r][2]));
    v.w = __builtin_amdgcn_exp2f((float)(Kc * accd[r][3]));
    *(float4*)(C + (size_t)(m0 + ty * 4 + r) * Hh + n0 + tx * 4) = v;
  }
}

// ---------------------------------------------------------------------------
// group4: sum over 4 h of u_h * tanh(s_h) where e_h = el*er = e^(2 s_h):
//   tanh = 1 - 2/(1+e);  common denominator -> 1 v_rcp per 4 terms:
//   = s4 - 2*(u0 d1 d2 d3 + u1 d0 d2 d3 + u2 d0 d1 d3 + u3 d0 d1 d2)/(d0 d1 d2 d3)
// d = 1+e in [1, ~3e6]; D4 <= ~1e26 -- no fp32 overflow.
// ---------------------------------------------------------------------------
__device__ __forceinline__ float group4(const float4 a, const float4 bv,
                                        const float4 u, const float s4) {
  const float d0 = __builtin_fmaf(a.x, bv.x, 1.0f);
  const float d1 = __builtin_fmaf(a.y, bv.y, 1.0f);
  const float d2 = __builtin_fmaf(a.z, bv.z, 1.0f);
  const float d3 = __builtin_fmaf(a.w, bv.w, 1.0f);
  const float p01 = d0 * d1;
  const float p23 = d2 * d3;
  const float D = p01 * p23;
  float n01 = u.x * d1;
  n01 = __builtin_fmaf(u.y, d0, n01);
  float n23 = u.z * d3;
  n23 = __builtin_fmaf(u.w, d2, n23);
  float num = n01 * p23;
  num = __builtin_fmaf(n23, p01, num);
  const float r = __builtin_amdgcn_rcpf(D);
  return __builtin_fmaf(-2.0f, num * r, s4);
}

// Epilogue for one output element
__device__ __forceinline__ void emit(const int b, const int i, const int j,
                                     float x, float* __restrict__ out) {
  if (i == j) x -= 1e8f;  // self-mask, fp32 like the reference

  const double pd = 1.0 / (1.0 + exp(-(double)x));
  const float pf = (float)pd;

  const uint32_t n = ((uint32_t)i * Bb + (uint32_t)b) * Ll + (uint32_t)j;
  const uint32_t bits = rng_bits(n);
  const float uu = __uint_as_float((bits >> 9) | 0x3f800000u) - 1.0f;
  const float samp = (uu < pf) ? 1.0f : 0.0f;

  const float ax = fabsf(x);
  const float l1p = log1pf(expf(-ax));
  const float sp_pos = fmaxf(x, 0.0f) + l1p;
  const float sp_neg = fmaxf(-x, 0.0f) + l1p;
  const float ent = pf * sp_neg + (1.0f - pf) * sp_pos;

  out[n] = samp;
  out[Nout + n] = x;
  out[2 * Nout + n] = ent;
}

// ---------------------------------------------------------------------------
// Kernel 2: 32x32 output tile per block, 2x2 micro-tile per thread.
// LDS reads per 4-h group serve 16 terms (4 pairs) -> half the bytes/term.
// 8 static fp32 accumulators (2 per pair, manual unroll-by-2), fp64 combine.
// ---------------------------------------------------------------------------
__global__ __launch_bounds__(256) void biaffine_main(
    const float* __restrict__ el, const float* __restrict__ er,
    const float* __restrict__ U, const float* __restrict__ biasp,
    float* __restrict__ out) {
  const int b = blockIdx.z;
  const int i0 = blockIdx.y * 32;
  const int j0 = blockIdx.x * 32;

  // stride 260 floats (16B-aligned rows); 260 % 32 = 4 -> 2-way alias (free)
  __shared__ float els[32][260];
  __shared__ float ers[32][260];
  __shared__ float us[Hh];
  __shared__ float us4[Hh / 4];

  const int t = threadIdx.x;
  if (t < 128) {
    const float4 u = ((const float4*)U)[t];
    *(float4*)&us[t * 4] = u;
    us4[t] = ((u.x + u.y) + u.z) + u.w;
  }

  const int ti = t >> 4;  // 0..15 -> i rows {ti, ti+16}
  const int tj = t & 15;  // 0..15 -> j rows {tj, tj+16}

  const float* elg = el + (size_t)(b * Ll + i0) * Hh;
  const float* erg = er + (size_t)(b * Ll + j0) * Hh;

  // acc[pair] split into even/odd-g chains (<=64 adds each)
  float e00 = 0.f, e01 = 0.f, e10 = 0.f, e11 = 0.f;
  float o00 = 0.f, o01 = 0.f, o10 = 0.f, o11 = 0.f;

  for (int ph = 0; ph < 2; ++ph) {
    __syncthreads();
#pragma unroll
    for (int rep = 0; rep < 8; ++rep) {
      const int idx = t + rep * 256;   // 0..2047
      const int r = idx >> 6;          // 0..31
      const int c = (idx & 63) * 4;    // 0..252
      *(float4*)&els[r][c] = *(const float4*)(elg + (size_t)r * Hh + ph * 256 + c);
      *(float4*)&ers[r][c] = *(const float4*)(erg + (size_t)r * Hh + ph * 256 + c);
    }
    __syncthreads();
    const float* ar0 = &els[ti][0];
    const float* ar1 = &els[ti + 16][0];
    const float* br0 = &ers[tj][0];
    const float* br1 = &ers[tj + 16][0];
    const float* urow = &us[ph * 256];
    const float* u4row = &us4[ph * 64];

#pragma unroll 2
    for (int g = 0; g < 64; g += 2) {
      {
        const int h = g * 4;
        const float4 a0 = *(const float4*)&ar0[h];
        const float4 a1 = *(const float4*)&ar1[h];
        const float4 b0 = *(const float4*)&br0[h];
        const float4 b1 = *(const float4*)&br1[h];
        const float4 u = *(const float4*)&urow[h];
        const float s4 = u4row[g];
        e00 += group4(a0, b0, u, s4);
        e01 += group4(a0, b1, u, s4);
        e10 += group4(a1, b0, u, s4);
        e11 += group4(a1, b1, u, s4);
      }
      {
        const int h = (g + 1) * 4;
        const float4 a0 = *(const float4*)&ar0[h];
        const float4 a1 = *(const float4*)&ar1[h];
        const float4 b0 = *(const float4*)&br0[h];
        const float4 b1 = *(const float4*)&br1[h];
        const float4 u = *(const float4*)&urow[h];
        const float s4 = u4row[g + 1];
        o00 += group4(a0, b0, u, s4);
        o01 += group4(a0, b1, u, s4);
        o10 += group4(a1, b0, u, s4);
        o11 += group4(a1, b1, u, s4);
      }
    }
  }

  const float bias = biasp[0];
  const int i_a = i0 + ti, i_b = i0 + 16 + ti;
  const int j_a = j0 + tj, j_b = j0 + 16 + tj;

  emit(b, i_a, j_a, (float)((double)e00 + (double)o00) + bias, out);
  emit(b, i_a, j_b, (float)((double)e01 + (double)o01) + bias, out);
  emit(b, i_b, j_a, (float)((double)e10 + (double)o10) + bias, out);
  emit(b, i_b, j_b, (float)((double)e11 + (double)o11) + bias, out);
}

// ---------------------------------------------------------------------------
extern "C" void kernel_launch(void* const* d_in, const int* in_sizes, int n_in,
                              void* d_out, int out_size, void* d_ws,
                              size_t ws_size, hipStream_t stream) {
  const float* enc = (const float*)d_in[0];  // [B,L,D]
  const float* Wl = (const float*)d_in[1];   // [D,H]
  const float* Wr = (const float*)d_in[2];   // [D,H]
  const float* U = (const float*)d_in[3];    // [H]
  const float* lb = (const float*)d_in[4];   // [1]
  float* out = (float*)d_out;

  float* el = (float*)d_ws;                  // exp2(Kc*dot_l): [B*L, H] = 4 MB
  float* er = el + (size_t)Bb * Ll * Hh;     // exp2(Kc*dot_r): [B*L, H] = 4 MB

  gemm_proj<<<dim3(2048 / 64, Hh / 64, 2), 256, 0, stream>>>(enc, Wl, Wr, el, er);
  biaffine_main<<<dim3(Ll / 32, Ll / 32, Bb), 256, 0, stream>>>(el, er, U, lb, out);
}

// Round 5
// 130.755 us; speedup vs baseline: 2.3594x; 1.0297x over previous
//
#include <hip/hip_runtime.h>
#include <stdint.h>

// Problem constants (B, L, D, H) = (8, 256, 512, 512)
#define Bb 8
#define Ll 256
#define Dd 512
#define Hh 512
#define Nout (Ll * Bb * Ll)  // 524288 elements per output tensor

#define Kc 2.8853900817779268  // 2/ln(2):  exp2(Kc*s) = e^(2s)

// JAX threefry mode: 1 = partitionable (default since jax 0.4.30)
#define RNG_PARTITIONABLE 1

// ---------------------------------------------------------------------------
// Threefry2x32 with key = (0, 42)  (jax.random.key(42))
// ---------------------------------------------------------------------------
__device__ __forceinline__ uint32_t rotl32(uint32_t v, int s) {
  return (v << s) | (v >> (32 - s));
}
__device__ __forceinline__ void tf_round(uint32_t& x0, uint32_t& x1, int r) {
  x0 += x1;
  x1 = rotl32(x1, r);
  x1 ^= x0;
}
__device__ __forceinline__ uint2 threefry2x32_k042(uint32_t x0, uint32_t x1) {
  const uint32_t k0 = 0u;
  const uint32_t k1 = 42u;
  const uint32_t k2 = 0x1BD11BDAu ^ k0 ^ k1;
  x0 += k0; x1 += k1;
  tf_round(x0, x1, 13); tf_round(x0, x1, 15); tf_round(x0, x1, 26); tf_round(x0, x1, 6);
  x0 += k1; x1 += k2 + 1u;
  tf_round(x0, x1, 17); tf_round(x0, x1, 29); tf_round(x0, x1, 16); tf_round(x0, x1, 24);
  x0 += k2; x1 += k0 + 2u;
  tf_round(x0, x1, 13); tf_round(x0, x1, 15); tf_round(x0, x1, 26); tf_round(x0, x1, 6);
  x0 += k0; x1 += k1 + 3u;
  tf_round(x0, x1, 17); tf_round(x0, x1, 29); tf_round(x0, x1, 16); tf_round(x0, x1, 24);
  x0 += k1; x1 += k2 + 4u;
  tf_round(x0, x1, 13); tf_round(x0, x1, 15); tf_round(x0, x1, 26); tf_round(x0, x1, 6);
  x0 += k2; x1 += k0 + 5u;
  return make_uint2(x0, x1);
}

__device__ __forceinline__ uint32_t rng_bits(uint32_t n) {
#if RNG_PARTITIONABLE
  uint2 o = threefry2x32_k042(0u, n);
  return o.x ^ o.y;
#else
  const uint32_t half = (uint32_t)(Nout / 2);
  if (n < half) {
    uint2 o = threefry2x32_k042(n, n + half);
    return o.x;
  } else {
    uint2 o = threefry2x32_k042(n - half, n);
    return o.y;
  }
#endif
}

// ---------------------------------------------------------------------------
// Kernel 1: el = exp2(Kc * (enc @ W_l)),  er = exp2(Kc * (enc @ W_r))
// (unchanged from R3/R4 for attribution; known LDS-bound ~43 us, MFMA next)
// ---------------------------------------------------------------------------
__global__ __launch_bounds__(256) void gemm_proj(
    const float* __restrict__ enc, const float* __restrict__ Wl,
    const float* __restrict__ Wr, float* __restrict__ el,
    float* __restrict__ er) {
  const float* W = (blockIdx.z == 0) ? Wl : Wr;
  float* C = (blockIdx.z == 0) ? el : er;
  const int m0 = blockIdx.x * 64;
  const int n0 = blockIdx.y * 64;

  __shared__ float As[2][32][68];
  __shared__ float Ws[2][32][68];

  const int t = threadIdx.x;
  const int tx = t & 15;
  const int ty = t >> 4;

  double accd[4][4];
#pragma unroll
  for (int r = 0; r < 4; ++r)
#pragma unroll
    for (int c = 0; c < 4; ++c) accd[r][c] = 0.0;

  float4 pa[2], pw[2];
#pragma unroll
  for (int r = 0; r < 2; ++r) {
    const int idx = t + r * 256;
    const int am = idx >> 3, akq = idx & 7;
    pa[r] = *(const float4*)(enc + (size_t)(m0 + am) * Dd + akq * 4);
    const int wk = idx >> 4, wnq = idx & 15;
    pw[r] = *(const float4*)(W + (size_t)wk * Hh + n0 + wnq * 4);
  }
#pragma unroll
  for (int r = 0; r < 2; ++r) {
    const int idx = t + r * 256;
    const int am = idx >> 3, akq = idx & 7;
    As[0][akq * 4 + 0][am] = pa[r].x;
    As[0][akq * 4 + 1][am] = pa[r].y;
    As[0][akq * 4 + 2][am] = pa[r].z;
    As[0][akq * 4 + 3][am] = pa[r].w;
    const int wk = idx >> 4, wnq = idx & 15;
    *(float4*)&Ws[0][wk][wnq * 4] = pw[r];
  }
  __syncthreads();

  for (int s = 0; s < 16; ++s) {
    const int buf = s & 1;
    if (s < 15) {
      const int k0 = (s + 1) * 32;
#pragma unroll
      for (int r = 0; r < 2; ++r) {
        const int idx = t + r * 256;
        const int am = idx >> 3, akq = idx & 7;
        pa[r] = *(const float4*)(enc + (size_t)(m0 + am) * Dd + k0 + akq * 4);
        const int wk = idx >> 4, wnq = idx & 15;
        pw[r] = *(const float4*)(W + (size_t)(k0 + wk) * Hh + n0 + wnq * 4);
      }
    }

    float accf[4][4];
#pragma unroll
    for (int r = 0; r < 4; ++r)
#pragma unroll
      for (int c = 0; c < 4; ++c) accf[r][c] = 0.0f;

#pragma unroll
    for (int k = 0; k < 32; ++k) {
      const float4 av = *(const float4*)&As[buf][k][ty * 4];
      const float4 bv = *(const float4*)&Ws[buf][k][tx * 4];
      accf[0][0] = __builtin_fmaf(av.x, bv.x, accf[0][0]);
      accf[0][1] = __builtin_fmaf(av.x, bv.y, accf[0][1]);
      accf[0][2] = __builtin_fmaf(av.x, bv.z, accf[0][2]);
      accf[0][3] = __builtin_fmaf(av.x, bv.w, accf[0][3]);
      accf[1][0] = __builtin_fmaf(av.y, bv.x, accf[1][0]);
      accf[1][1] = __builtin_fmaf(av.y, bv.y, accf[1][1]);
      accf[1][2] = __builtin_fmaf(av.y, bv.z, accf[1][2]);
      accf[1][3] = __builtin_fmaf(av.y, bv.w, accf[1][3]);
      accf[2][0] = __builtin_fmaf(av.z, bv.x, accf[2][0]);
      accf[2][1] = __builtin_fmaf(av.z, bv.y, accf[2][1]);
      accf[2][2] = __builtin_fmaf(av.z, bv.z, accf[2][2]);
      accf[2][3] = __builtin_fmaf(av.z, bv.w, accf[2][3]);
      accf[3][0] = __builtin_fmaf(av.w, bv.x, accf[3][0]);
      accf[3][1] = __builtin_fmaf(av.w, bv.y, accf[3][1]);
      accf[3][2] = __builtin_fmaf(av.w, bv.z, accf[3][2]);
      accf[3][3] = __builtin_fmaf(av.w, bv.w, accf[3][3]);
    }
#pragma unroll
    for (int r = 0; r < 4; ++r)
#pragma unroll
      for (int c = 0; c < 4; ++c) accd[r][c] += (double)accf[r][c];

    if (s < 15) {
      const int nb = buf ^ 1;
#pragma unroll
      for (int r = 0; r < 2; ++r) {
        const int idx = t + r * 256;
        const int am = idx >> 3, akq = idx & 7;
        As[nb][akq * 4 + 0][am] = pa[r].x;
        As[nb][akq * 4 + 1][am] = pa[r].y;
        As[nb][akq * 4 + 2][am] = pa[r].z;
        As[nb][akq * 4 + 3][am] = pa[r].w;
        const int wk = idx >> 4, wnq = idx & 15;
        *(float4*)&Ws[nb][wk][wnq * 4] = pw[r];
      }
    }
    __syncthreads();
  }

#pragma unroll
  for (int r = 0; r < 4; ++r) {
    float4 v;
    v.x = __builtin_amdgcn_exp2f((float)(Kc * accd[r][0]));
    v.y = __builtin_amdgcn_exp2f((float)(Kc * accd[r][1]));
    v.z = __builtin_amdgcn_exp2f((float)(Kc * accd[r][2]));
    v.w = __builtin_amdgcn_exp2f((float)(Kc * accd[r][3]));
    *(float4*)(C + (size_t)(m0 + ty * 4 + r) * Hh + n0 + tx * 4) = v;
  }
}

// ---------------------------------------------------------------------------
// group4_acc: S += num/D for 4 h-terms, where
//   sum_h u_h tanh(s_h) = sum(u) - 2*sum(num/D) over groups (e = el*er = e^2s,
//   tanh = 1 - 2/(1+e); common denominator over the 4-group).
// 12 VALU + 1 v_rcp per 4 terms. d in [1, ~2e5]; D <= ~2e21 (fp32 safe).
// ---------------------------------------------------------------------------
__device__ __forceinline__ void group4_acc(float& S, const float4 a,
                                           const float4 bv, const float4 u) {
  const float d0 = __builtin_fmaf(a.x, bv.x, 1.0f);
  const float d1 = __builtin_fmaf(a.y, bv.y, 1.0f);
  const float d2 = __builtin_fmaf(a.z, bv.z, 1.0f);
  const float d3 = __builtin_fmaf(a.w, bv.w, 1.0f);
  const float p01 = d0 * d1;
  const float p23 = d2 * d3;
  const float D = p01 * p23;
  float n01 = u.x * d1;
  n01 = __builtin_fmaf(u.y, d0, n01);
  float n23 = u.z * d3;
  n23 = __builtin_fmaf(u.w, d2, n23);
  float num = n01 * p23;
  num = __builtin_fmaf(n23, p01, num);
  S = __builtin_fmaf(num, __builtin_amdgcn_rcpf(D), S);
}

// ---------------------------------------------------------------------------
// Kernel 2a: partial x over a 64-h slice. 64x64 output tile, 4x4 micro-tile,
// split-K=8 (grid.z = b*8 + ks gives 1024 blocks = 4/CU, 35.3 KB LDS).
// part[ks][n] = sum_{h in slice} u_h tanh(.) = Usl - 2*S  (fp32)
// ---------------------------------------------------------------------------
__global__ __launch_bounds__(256) void biaffine_part(
    const float* __restrict__ el, const float* __restrict__ er,
    const float* __restrict__ U, float* __restrict__ part) {
  const int zz = blockIdx.z;
  const int b = zz & 7;
  const int ks = zz >> 3;  // 0..7
  const int i0 = blockIdx.y * 64;
  const int j0 = blockIdx.x * 64;
  const int h0 = ks * 64;

  // stride 68: 16B-aligned rows; 68*16 = 1088 = 0 mod 32 banks -> the 16
  // distinct rows touched per b128 read alias banks exactly 2-way (free).
  __shared__ float els[64][68];
  __shared__ float ers[64][68];
  __shared__ float us[64];

  const int t = threadIdx.x;
  if (t < 16) *(float4*)&us[t * 4] = *(const float4*)(U + h0 + t * 4);

  const float* elg = el + (size_t)(b * Ll + i0) * Hh + h0;
  const float* erg = er + (size_t)(b * Ll + j0) * Hh + h0;
#pragma unroll
  for (int rep = 0; rep < 4; ++rep) {
    const int idx = t + rep * 256;  // 0..1023
    const int r = idx >> 4;         // 0..63
    const int c = (idx & 15) * 4;   // 0..60
    *(float4*)&els[r][c] = *(const float4*)(elg + (size_t)r * Hh + c);
    *(float4*)&ers[r][c] = *(const float4*)(erg + (size_t)r * Hh + c);
  }
  __syncthreads();

  // per-thread redundant slice-sum of u (all threads -> identical value)
  float usl = 0.0f;
#pragma unroll
  for (int q = 0; q < 16; ++q) {
    const float4 u = *(const float4*)&us[q * 4];
    usl += ((u.x + u.y) + u.z) + u.w;
  }

  const int ti = t >> 4;  // i in {ti, ti+16, ti+32, ti+48}
  const int tj = t & 15;  // j in {tj, tj+16, tj+32, tj+48}

  float S[4][4];
#pragma unroll
  for (int r = 0; r < 4; ++r)
#pragma unroll
    for (int c = 0; c < 4; ++c) S[r][c] = 0.0f;

#pragma unroll 2
  for (int g = 0; g < 16; ++g) {
    const int h = g * 4;
    const float4 u = *(const float4*)&us[h];
    float4 av[4], bv[4];
#pragma unroll
    for (int c = 0; c < 4; ++c) {
      av[c] = *(const float4*)&els[ti + 16 * c][h];
      bv[c] = *(const float4*)&ers[tj + 16 * c][h];
    }
#pragma unroll
    for (int r = 0; r < 4; ++r)
#pragma unroll
      for (int c = 0; c < 4; ++c) group4_acc(S[r][c], av[r], bv[c], u);
  }

  float* pslice = part + (size_t)ks * Nout;
#pragma unroll
  for (int r = 0; r < 4; ++r) {
    const int i = i0 + ti + 16 * r;
#pragma unroll
    for (int c = 0; c < 4; ++c) {
      const int j = j0 + tj + 16 * c;
      const uint32_t n = ((uint32_t)i * Bb + (uint32_t)b) * Ll + (uint32_t)j;
      pslice[n] = __builtin_fmaf(-2.0f, S[r][c], usl);
    }
  }
}

// ---------------------------------------------------------------------------
// Kernel 2b: sum the 8 slice partials (fixed order, fp64), add bias, emit
// samples / mask_scores / entropy. 4 consecutive elements per thread.
// ---------------------------------------------------------------------------
__global__ __launch_bounds__(256) void biaffine_emit(
    const float* __restrict__ part, const float* __restrict__ biasp,
    float* __restrict__ out) {
  const uint32_t n4 = (blockIdx.x * 256u + threadIdx.x) * 4u;
  double s0 = 0.0, s1 = 0.0, s2 = 0.0, s3 = 0.0;
#pragma unroll
  for (int k = 0; k < 8; ++k) {
    const float4 v = *(const float4*)(part + (size_t)k * Nout + n4);
    s0 += (double)v.x;
    s1 += (double)v.y;
    s2 += (double)v.z;
    s3 += (double)v.w;
  }
  const float bias = biasp[0];
  const double sv[4] = {s0, s1, s2, s3};

  float4 samp4, x4, ent4;
  float* sp = &samp4.x;
  float* xp = &x4.x;
  float* ep = &ent4.x;
#pragma unroll
  for (int q = 0; q < 4; ++q) {
    const uint32_t n = n4 + q;
    const int i = (int)(n >> 11);
    const int j = (int)(n & 255u);
    float x = (float)sv[q] + bias;
    if (i == j) x -= 1e8f;  // self-mask

    const double pd = 1.0 / (1.0 + exp(-(double)x));
    const float pf = (float)pd;

    const uint32_t bits = rng_bits(n);
    const float uu = __uint_as_float((bits >> 9) | 0x3f800000u) - 1.0f;
    sp[q] = (uu < pf) ? 1.0f : 0.0f;
    xp[q] = x;

    const float ax = fabsf(x);
    const float l1p = log1pf(expf(-ax));
    const float sp_pos = fmaxf(x, 0.0f) + l1p;
    const float sp_neg = fmaxf(-x, 0.0f) + l1p;
    ep[q] = pf * sp_neg + (1.0f - pf) * sp_pos;
  }
  *(float4*)(out + n4) = samp4;
  *(float4*)(out + Nout + n4) = x4;
  *(float4*)(out + 2 * (size_t)Nout + n4) = ent4;
}

// ---------------------------------------------------------------------------
extern "C" void kernel_launch(void* const* d_in, const int* in_sizes, int n_in,
                              void* d_out, int out_size, void* d_ws,
                              size_t ws_size, hipStream_t stream) {
  const float* enc = (const float*)d_in[0];  // [B,L,D]
  const float* Wl = (const float*)d_in[1];   // [D,H]
  const float* Wr = (const float*)d_in[2];   // [D,H]
  const float* U = (const float*)d_in[3];    // [H]
  const float* lb = (const float*)d_in[4];   // [1]
  float* out = (float*)d_out;

  float* el = (float*)d_ws;                    // exp2(Kc*dot_l): 4 MB
  float* er = el + (size_t)Bb * Ll * Hh;       // exp2(Kc*dot_r): 4 MB
  float* part = er + (size_t)Bb * Ll * Hh;     // 8 x [L*B*L] fp32 = 16 MB

  gemm_proj<<<dim3(2048 / 64, Hh / 64, 2), 256, 0, stream>>>(enc, Wl, Wr, el, er);
  biaffine_part<<<dim3(Ll / 64, Ll / 64, Bb * 8), 256, 0, stream>>>(el, er, U, part);
  biaffine_emit<<<dim3(Nout / 1024), 256, 0, stream>>>(part, lb, out);
}